// Round 1
// baseline (209.515 us; speedup 1.0000x reference)
//
#include <hip/hip_runtime.h>

// Conv1dFFT via polyphase: y[b,n] = IFFT_8192( sum_p G_p * FFT_8192(x_polyphase_p) )[n]
// B=256 rows, T=65536, k=8, Tk=8192.
// Real polyphase components packed in pairs into 4 complex FFTs; Hermitian split
// folded into precomputed P/Q (stored bit-reversed so DIF-fwd / DIT-inv needs no reorder).

#define TK      8192
#define LOG2TK  13
#define HALF_TK 4096
#define KFOLD   8
#define NPAIR   4
#define TFULL   65536
#define NT      1024

__device__ __forceinline__ float2 cmul(float2 a, float2 b) {
    return make_float2(a.x * b.x - a.y * b.y, a.x * b.y + a.y * b.x);
}
__device__ __forceinline__ unsigned br13(unsigned r) { return __brev(r) >> 19u; }

// Precomputed tables (rewritten every launch -> deterministic)
__device__ float2 g_W[HALF_TK];        // e^{-2pi i t/8192}, t in [0,4096)
__device__ float2 g_P[NPAIR * TK];     // bit-reversed order
__device__ float2 g_Q[NPAIR * TK];     // bit-reversed order

__global__ void build_twiddle_kernel() {
    int t = blockIdx.x * blockDim.x + threadIdx.x;
    if (t < HALF_TK) {
        double ang = -2.0 * 3.14159265358979323846 * (double)t / (double)TK;
        g_W[t] = make_float2((float)cos(ang), (float)sin(ang));
    }
}

__global__ void build_pq_kernel(const float* __restrict__ filt) {
    int t = blockIdx.x * blockDim.x + threadIdx.x;
    if (t >= TK) return;
    float fm[KFOLD];
#pragma unroll
    for (int m = 0; m < KFOLD; ++m) fm[m] = filt[m * TK + t];
    float2 G[KFOLD];
#pragma unroll
    for (int p = 0; p < KFOLD; ++p) {
        double sr = 0.0, si = 0.0;
#pragma unroll
        for (int m = 0; m < KFOLD; ++m) {
            double ang = -2.0 * 3.14159265358979323846 * (double)((p * m) & 7) / 8.0;
            sr += (double)fm[m] * cos(ang);
            si += (double)fm[m] * sin(ang);
        }
        // G_p = e^{-2pi i p t / 65536} * S_p / 8
        double ang2 = -2.0 * 3.14159265358979323846 * (double)(p * t) / (double)TFULL;
        double c2 = cos(ang2), s2 = sin(ang2);
        G[p] = make_float2((float)((sr * c2 - si * s2) * 0.125),
                           (float)((sr * s2 + si * c2) * 0.125));
    }
    const float norm = 0.5f / (float)TK;   // 0.5 Hermitian split, 1/8192 ifft norm
    unsigned r = br13((unsigned)t);
#pragma unroll
    for (int j = 0; j < NPAIR; ++j) {
        float2 g0 = G[2 * j], g1 = G[2 * j + 1];
        // P = 0.5*(g0 - i*g1), Q = 0.5*(g0 + i*g1)   (times ifft norm)
        g_P[j * TK + r] = make_float2((g0.x + g1.y) * norm, (g0.y - g1.x) * norm);
        g_Q[j * TK + r] = make_float2((g0.x - g1.y) * norm, (g0.y + g1.x) * norm);
    }
}

__global__ __launch_bounds__(NT, 1)
void conv_fft_kernel(const float* __restrict__ x, float2* __restrict__ out) {
    __shared__ float2 buf[TK];   // 64 KB
    const int tid = threadIdx.x;
    const int b = blockIdx.x;
    const float2* __restrict__ xrow =
        reinterpret_cast<const float2*>(x) + (size_t)b * (TFULL / 2);

    float2 acc[TK / NT];
#pragma unroll
    for (int c = 0; c < TK / NT; ++c) acc[c] = make_float2(0.f, 0.f);

    for (int j = 0; j < NPAIR; ++j) {
        // load packed pair j: z[u] = x[8u+2j] + i x[8u+2j+1]  == float2 at index 4u+j
#pragma unroll
        for (int c = 0; c < TK / NT; ++c) {
            int u = c * NT + tid;
            buf[u] = xrow[4 * u + j];
        }
        __syncthreads();

        // forward FFT: in-place radix-2 DIF, natural -> bit-reversed
        int logh = LOG2TK - 1;
        for (int h = HALF_TK; h >= 1; h >>= 1, --logh) {
#pragma unroll
            for (int c = 0; c < HALF_TK / NT; ++c) {
                int idx = c * NT + tid;
                int q = idx & (h - 1);
                int blk = idx >> logh;
                int i = (blk << (logh + 1)) + q;
                float2 a = buf[i];
                float2 bv = buf[i + h];
                float2 w = g_W[q << (LOG2TK - 1 - logh)];
                buf[i]     = make_float2(a.x + bv.x, a.y + bv.y);
                buf[i + h] = cmul(make_float2(a.x - bv.x, a.y - bv.y), w);
            }
            __syncthreads();
        }

        // accumulate: position r holds Z[br(r)];  y_hat += Z*P + conj(Z[-t])*Q
#pragma unroll
        for (int c = 0; c < TK / NT; ++c) {
            int r = c * NT + tid;
            unsigned t = br13((unsigned)r);
            unsigned tm = (TK - t) & (TK - 1);
            int r2 = (int)br13(tm);
            float2 Zt = buf[r];
            float2 Zm = buf[r2];
            float2 Pv = g_P[j * TK + r];
            float2 Qv = g_Q[j * TK + r];
            acc[c].x += Zt.x * Pv.x - Zt.y * Pv.y + Zm.x * Qv.x + Zm.y * Qv.y;
            acc[c].y += Zt.x * Pv.y + Zt.y * Pv.x + Zm.x * Qv.y - Zm.y * Qv.x;
        }
        __syncthreads();   // all reads of buf done before next j's load
    }

    // y_hat (bit-reversed order) -> buf
#pragma unroll
    for (int c = 0; c < TK / NT; ++c) buf[c * NT + tid] = acc[c];
    __syncthreads();

    // inverse FFT: in-place radix-2 DIT, bit-reversed -> natural, conj twiddles
    {
        int logh = 0;
        for (int h = 1; h <= HALF_TK; h <<= 1, ++logh) {
#pragma unroll
            for (int c = 0; c < HALF_TK / NT; ++c) {
                int idx = c * NT + tid;
                int q = idx & (h - 1);
                int blk = idx >> logh;
                int i = (blk << (logh + 1)) + q;
                float2 w = g_W[q << (LOG2TK - 1 - logh)];
                w.y = -w.y;
                float2 a = buf[i];
                float2 bv = cmul(buf[i + h], w);
                buf[i]     = make_float2(a.x + bv.x, a.y + bv.y);
                buf[i + h] = make_float2(a.x - bv.x, a.y - bv.y);
            }
            __syncthreads();
        }
    }

    // write out: [B, 1, 8192, 2] -> float2 per n
    float2* __restrict__ orow = out + (size_t)b * TK;
#pragma unroll
    for (int c = 0; c < TK / NT; ++c) {
        int n = c * NT + tid;
        orow[n] = buf[n];
    }
}

extern "C" void kernel_launch(void* const* d_in, const int* in_sizes, int n_in,
                              void* d_out, int out_size, void* d_ws, size_t ws_size,
                              hipStream_t stream) {
    const float* x    = (const float*)d_in[0];
    const float* filt = (const float*)d_in[1];
    const int T = in_sizes[1];          // 65536
    const int B = in_sizes[0] / T;      // 256 (rows = B*C)
    (void)n_in; (void)d_ws; (void)ws_size; (void)out_size; (void)T;

    build_twiddle_kernel<<<HALF_TK / 256, 256, 0, stream>>>();
    build_pq_kernel<<<TK / 256, 256, 0, stream>>>(filt);
    conv_fft_kernel<<<B, NT, 0, stream>>>(x, (float2*)d_out);
}

// Round 2
// 120.363 us; speedup vs baseline: 1.7407x; 1.7407x over previous
//
#include <hip/hip_runtime.h>

// Conv1dFFT via polyphase: y[b] = IFFT_8192( sum_p G_p * FFT_8192(x_polyphase_p) )
// Radix-8 register passes (3 stages each), outer stage merged with global I/O.
// Identical 13-stage DIF/DIT sequence as the verified radix-2 version.

#define TK      8192
#define LOG2TK  13
#define HALF_TK 4096
#define KFOLD   8
#define NPAIR   4
#define TFULL   65536
#define NT      1024
#define RSQ2    0.70710678118654752440f

// LDS bank-conflict swizzle (bijective: low 4 bits XOR bits 4..7)
#define SW(i) ((i) ^ (((i) >> 4) & 15))

__device__ __forceinline__ float2 cmul(float2 a, float2 b) {
    return make_float2(a.x * b.x - a.y * b.y, a.x * b.y + a.y * b.x);
}
__device__ __forceinline__ unsigned br13(unsigned r) { return __brev(r) >> 19u; }

__device__ float2 g_W[HALF_TK];        // e^{-2pi i t/8192}
__device__ float2 g_P[NPAIR * TK];     // bit-reversed order
__device__ float2 g_Q[NPAIR * TK];     // bit-reversed order

__global__ void build_twiddle_kernel() {
    int t = blockIdx.x * blockDim.x + threadIdx.x;
    if (t < HALF_TK) {
        double ang = -2.0 * 3.14159265358979323846 * (double)t / (double)TK;
        g_W[t] = make_float2((float)cos(ang), (float)sin(ang));
    }
}

__global__ void build_pq_kernel(const float* __restrict__ filt) {
    int t = blockIdx.x * blockDim.x + threadIdx.x;
    if (t >= TK) return;
    float fm[KFOLD];
#pragma unroll
    for (int m = 0; m < KFOLD; ++m) fm[m] = filt[m * TK + t];
    float2 G[KFOLD];
#pragma unroll
    for (int p = 0; p < KFOLD; ++p) {
        double sr = 0.0, si = 0.0;
#pragma unroll
        for (int m = 0; m < KFOLD; ++m) {
            double ang = -2.0 * 3.14159265358979323846 * (double)((p * m) & 7) / 8.0;
            sr += (double)fm[m] * cos(ang);
            si += (double)fm[m] * sin(ang);
        }
        double ang2 = -2.0 * 3.14159265358979323846 * (double)(p * t) / (double)TFULL;
        double c2 = cos(ang2), s2 = sin(ang2);
        G[p] = make_float2((float)((sr * c2 - si * s2) * 0.125),
                           (float)((sr * s2 + si * c2) * 0.125));
    }
    const float norm = 0.5f / (float)TK;
    unsigned r = br13((unsigned)t);
#pragma unroll
    for (int j = 0; j < NPAIR; ++j) {
        float2 g0 = G[2 * j], g1 = G[2 * j + 1];
        g_P[j * TK + r] = make_float2((g0.x + g1.y) * norm, (g0.y - g1.x) * norm);
        g_Q[j * TK + r] = make_float2((g0.x - g1.y) * norm, (g0.y + g1.x) * norm);
    }
}

// Forward DIF radix-8 pass: stages (4s, 2s, s), s = 1<<C.
// Twiddles: stage 4s -> W[(q0+t*s)<<(10-C)] = w1*u8^t ; stage 2s -> w2*(-i)^(t&1) ; stage s -> w3.
template<int C>
__device__ __forceinline__ void fwd_pass(float2* buf, int tid) {
    const int s = 1 << C;
    const int q0 = tid & (s - 1);
    const int i0 = ((tid >> C) << (C + 3)) + q0;
    float2 e[8];
#pragma unroll
    for (int t = 0; t < 8; ++t) e[t] = buf[SW(i0 + t * s)];
    float2 w1, w2, w3;
    if (C == 0) { w1 = make_float2(1.f, 0.f); w2 = w1; w3 = w1; }
    else { w1 = g_W[q0 << (10 - C)]; w2 = cmul(w1, w1); w3 = cmul(w2, w2); }
    // stage h = 4s
#pragma unroll
    for (int t = 0; t < 4; ++t) {
        float2 a = e[t], b = e[t + 4];
        float2 d = make_float2(a.x - b.x, a.y - b.y);
        e[t] = make_float2(a.x + b.x, a.y + b.y);
        d = cmul(d, w1);
        if (t == 1)      d = make_float2(RSQ2 * (d.x + d.y), RSQ2 * (d.y - d.x));
        else if (t == 2) d = make_float2(d.y, -d.x);
        else if (t == 3) d = make_float2(RSQ2 * (d.y - d.x), -RSQ2 * (d.x + d.y));
        e[t + 4] = d;
    }
    // stage h = 2s
#pragma unroll
    for (int t0 = 0; t0 < 8; t0 += 4) {
#pragma unroll
        for (int t = 0; t < 2; ++t) {
            int i = t0 + t;
            float2 a = e[i], b = e[i + 2];
            float2 d = make_float2(a.x - b.x, a.y - b.y);
            e[i] = make_float2(a.x + b.x, a.y + b.y);
            d = cmul(d, w2);
            if (t == 1) d = make_float2(d.y, -d.x);
            e[i + 2] = d;
        }
    }
    // stage h = s
#pragma unroll
    for (int t = 0; t < 8; t += 2) {
        float2 a = e[t], b = e[t + 1];
        float2 d = make_float2(a.x - b.x, a.y - b.y);
        e[t] = make_float2(a.x + b.x, a.y + b.y);
        e[t + 1] = cmul(d, w3);
    }
#pragma unroll
    for (int t = 0; t < 8; ++t) buf[SW(i0 + t * s)] = e[t];
}

// Inverse DIT radix-8 pass: stages (s, 2s, 4s), conjugated twiddles.
template<int C>
__device__ __forceinline__ void inv_pass(float2* buf, int tid) {
    const int s = 1 << C;
    const int q0 = tid & (s - 1);
    const int i0 = ((tid >> C) << (C + 3)) + q0;
    float2 e[8];
#pragma unroll
    for (int t = 0; t < 8; ++t) e[t] = buf[SW(i0 + t * s)];
    float2 v1, v2, v3;
    if (C == 0) { v1 = make_float2(1.f, 0.f); v2 = v1; v3 = v1; }
    else { v1 = g_W[q0 << (10 - C)]; v1.y = -v1.y; v2 = cmul(v1, v1); v3 = cmul(v2, v2); }
    // stage h = s
#pragma unroll
    for (int t = 0; t < 8; t += 2) {
        float2 b = cmul(e[t + 1], v3);
        float2 a = e[t];
        e[t]     = make_float2(a.x + b.x, a.y + b.y);
        e[t + 1] = make_float2(a.x - b.x, a.y - b.y);
    }
    // stage h = 2s  (twiddle v2 * (+i)^(t&1))
#pragma unroll
    for (int t0 = 0; t0 < 8; t0 += 4) {
#pragma unroll
        for (int t = 0; t < 2; ++t) {
            int i = t0 + t;
            float2 b = cmul(e[i + 2], v2);
            if (t == 1) b = make_float2(-b.y, b.x);
            float2 a = e[i];
            e[i]     = make_float2(a.x + b.x, a.y + b.y);
            e[i + 2] = make_float2(a.x - b.x, a.y - b.y);
        }
    }
    // stage h = 4s  (twiddle v1 * conj(u8)^t, conj(u8) = (R, R))
#pragma unroll
    for (int t = 0; t < 4; ++t) {
        float2 b = cmul(e[t + 4], v1);
        if (t == 1)      b = make_float2(RSQ2 * (b.x - b.y), RSQ2 * (b.x + b.y));
        else if (t == 2) b = make_float2(-b.y, b.x);
        else if (t == 3) b = make_float2(-RSQ2 * (b.x + b.y), RSQ2 * (b.x - b.y));
        float2 a = e[t];
        e[t]     = make_float2(a.x + b.x, a.y + b.y);
        e[t + 4] = make_float2(a.x - b.x, a.y - b.y);
    }
#pragma unroll
    for (int t = 0; t < 8; ++t) buf[SW(i0 + t * s)] = e[t];
}

__global__ __launch_bounds__(NT, 4)
void conv_fft_kernel(const float* __restrict__ x, float2* __restrict__ out) {
    __shared__ float2 buf[TK];   // 64 KB
    const int tid = threadIdx.x;
    const int b = blockIdx.x;
    const float2* __restrict__ xrow =
        reinterpret_cast<const float2*>(x) + (size_t)b * (TFULL / 2);

    float2 acc[8];
#pragma unroll
    for (int c = 0; c < 8; ++c) acc[c] = make_float2(0.f, 0.f);

    for (int j = 0; j < NPAIR; ++j) {
        // global load fused with first DIF stage (h = 4096)
#pragma unroll
        for (int c4 = 0; c4 < 4; ++c4) {
            int u = c4 * NT + tid;
            float2 a  = xrow[4 * u + j];
            float2 bb = xrow[4 * (u + HALF_TK) + j];
            buf[SW(u)] = make_float2(a.x + bb.x, a.y + bb.y);
            float2 d = make_float2(a.x - bb.x, a.y - bb.y);
            buf[SW(u + HALF_TK)] = cmul(d, g_W[u]);
        }
        __syncthreads();
        fwd_pass<9>(buf, tid); __syncthreads();   // stages 2048,1024,512
        fwd_pass<6>(buf, tid); __syncthreads();   // stages 256,128,64
        fwd_pass<3>(buf, tid); __syncthreads();   // stages 32,16,8
        fwd_pass<0>(buf, tid); __syncthreads();   // stages 4,2,1
        // accumulate: position r holds Z[br(r)];  y_hat += Z*P + conj(Z[-t])*Q
#pragma unroll
        for (int c = 0; c < 8; ++c) {
            int r = c * NT + tid;
            unsigned t = br13((unsigned)r);
            unsigned tm = (TK - t) & (TK - 1);
            int r2 = (int)br13(tm);
            float2 Zt = buf[SW(r)];
            float2 Zm = buf[SW(r2)];
            float2 Pv = g_P[j * TK + r];
            float2 Qv = g_Q[j * TK + r];
            acc[c].x += Zt.x * Pv.x - Zt.y * Pv.y + Zm.x * Qv.x + Zm.y * Qv.y;
            acc[c].y += Zt.x * Pv.y + Zt.y * Pv.x + Zm.x * Qv.y - Zm.y * Qv.x;
        }
        __syncthreads();
    }

    // y_hat (bit-reversed) -> LDS
#pragma unroll
    for (int c = 0; c < 8; ++c) buf[SW(c * NT + tid)] = acc[c];
    __syncthreads();

    inv_pass<0>(buf, tid); __syncthreads();   // stages 1,2,4
    inv_pass<3>(buf, tid); __syncthreads();   // stages 8,16,32
    inv_pass<6>(buf, tid); __syncthreads();   // stages 64,128,256
    inv_pass<9>(buf, tid); __syncthreads();   // stages 512,1024,2048
    // final DIT stage (h = 4096) fused with global store
    float2* __restrict__ orow = out + (size_t)b * TK;
#pragma unroll
    for (int c4 = 0; c4 < 4; ++c4) {
        int u = c4 * NT + tid;
        float2 a = buf[SW(u)];
        float2 w = g_W[u]; w.y = -w.y;
        float2 bb = cmul(buf[SW(u + HALF_TK)], w);
        orow[u]           = make_float2(a.x + bb.x, a.y + bb.y);
        orow[u + HALF_TK] = make_float2(a.x - bb.x, a.y - bb.y);
    }
}

extern "C" void kernel_launch(void* const* d_in, const int* in_sizes, int n_in,
                              void* d_out, int out_size, void* d_ws, size_t ws_size,
                              hipStream_t stream) {
    const float* x    = (const float*)d_in[0];
    const float* filt = (const float*)d_in[1];
    const int T = in_sizes[1];          // 65536
    const int B = in_sizes[0] / T;      // 256 rows
    (void)n_in; (void)d_ws; (void)ws_size; (void)out_size; (void)T;

    build_twiddle_kernel<<<HALF_TK / 256, 256, 0, stream>>>();
    build_pq_kernel<<<TK / 256, 256, 0, stream>>>(filt);
    conv_fft_kernel<<<B, NT, 0, stream>>>(x, (float2*)d_out);
}